// Round 17
// baseline (186.720 us; speedup 1.0000x reference)
//
#include <hip/hip_runtime.h>

#define N_NODES 100000
#define N_EDGES 3200000
#define IN_DIM 32
#define HID 64
#define BSHIFT 8
#define BNODES 256                              // nodes per bucket
#define NB ((N_NODES + BNODES - 1) / BNODES)    // 391 buckets
#define NWG 256                                 // WGs for count/place
#define CHUNK (N_EDGES / NWG)                   // 12500 edges per WG (exact)
// segment bytes per (WG,bucket) = 4*CHUNK/NB ~= 128B >= 64B line (KEY!)
#define XBLOCKS ((N_NODES * IN_DIM + 255) / 256)  // 12500

typedef unsigned short u16;
typedef unsigned char u8;
typedef _Float16 h2 __attribute__((ext_vector_type(2)));
typedef _Float16 half8 __attribute__((ext_vector_type(8)));
typedef float float4v __attribute__((ext_vector_type(4)));
typedef float f32x2 __attribute__((ext_vector_type(2)));

__device__ __forceinline__ h2 as_h2(unsigned u) {
  return __builtin_bit_cast(h2, u);
}
__device__ __forceinline__ unsigned as_u(h2 v) {
  return __builtin_bit_cast(unsigned, v);
}
__device__ __forceinline__ h2 shfl_xor_h2(h2 v, int m) {
  int i = __builtin_bit_cast(int, v);
  i = __shfl_xor(i, m, 64);
  return __builtin_bit_cast(h2, i);
}
__device__ __forceinline__ u16 f2h(float f) {
  _Float16 h = (_Float16)f;
  return __builtin_bit_cast(u16, h);
}
__device__ __forceinline__ unsigned scale_h2(unsigned u, float rinv) {
  h2 v = as_h2(u);
  h2 o;
  o.x = (_Float16)((float)v.x * rinv);
  o.y = (_Float16)((float)v.y * rinv);
  return as_u(o);
}
__device__ __forceinline__ unsigned pack2_h(float a, float b) {
  h2 o;
  o.x = (_Float16)a;
  o.y = (_Float16)b;
  return as_u(o);
}

// ---------------------------------------------------------------------------
// csr_count with FUSED prep: blocks [0,NWG) do the bucket histogram;
// blocks [NWG, NWG+XBLOCKS) convert x -> {xh (f16), xq (fp8)}; last block
// converts the weights.
// ---------------------------------------------------------------------------
__global__ __launch_bounds__(256) void csr_count(
    const int* __restrict__ dst, int* __restrict__ counts,
    const float* __restrict__ x, u16* __restrict__ xh, u8* __restrict__ xq,
    const float* __restrict__ w1l, const float* __restrict__ w1r,
    const float* __restrict__ w2l, const float* __restrict__ w2r,
    u16* __restrict__ w1lf, u16* __restrict__ w1rf,
    u16* __restrict__ w2lf, u16* __restrict__ w2rf) {
  int b = blockIdx.x, tid = threadIdx.x;
  if (b < NWG) {
    __shared__ int h[NB];
    for (int i = tid; i < NB; i += 256) h[i] = 0;
    __syncthreads();
    const int4* d4 = (const int4*)(dst + b * CHUNK);
    for (int i = tid; i < CHUNK / 4; i += 256) {
      int4 v = d4[i];
      atomicAdd(&h[v.x >> BSHIFT], 1);
      atomicAdd(&h[v.y >> BSHIFT], 1);
      atomicAdd(&h[v.z >> BSHIFT], 1);
      atomicAdd(&h[v.w >> BSHIFT], 1);
    }
    __syncthreads();
    for (int i = tid; i < NB; i += 256) counts[i * NWG + b] = h[i];
  } else if (b < NWG + XBLOCKS) {
    int i = (b - NWG) * 256 + tid;
    if (i < N_NODES * IN_DIM) {
      float v = x[i];
      xh[i] = f2h(v);
      int enc = __builtin_amdgcn_cvt_pk_fp8_f32(v, v, 0, false);
      xq[i] = (u8)(enc & 0xff);
    }
  } else {
    for (int i = tid; i < HID * IN_DIM; i += 256) {
      w1lf[i] = f2h(w1l[i]);
      w1rf[i] = f2h(w1r[i]);
    }
    for (int i = tid; i < HID * HID; i += 256) {
      w2lf[i] = f2h(w2l[i]);
      w2rf[i] = f2h(w2r[i]);
    }
  }
}

__global__ __launch_bounds__(256) void csr_scan_w(
    int* __restrict__ counts, int* __restrict__ btot) {
  __shared__ int s[256];
  int b = blockIdx.x, tid = threadIdx.x;
  int v = counts[b * NWG + tid];
  s[tid] = v;
  __syncthreads();
  for (int off = 1; off < 256; off <<= 1) {
    int t = (tid >= off) ? s[tid - off] : 0;
    __syncthreads();
    s[tid] += t;
    __syncthreads();
  }
  counts[b * NWG + tid] = s[tid] - v;
  if (tid == 255) btot[b] = s[255];
}

__global__ __launch_bounds__(256) void csr_scan_b(
    const int* __restrict__ btot, int* __restrict__ bbase) {
  __shared__ int s[256];
  int tid = threadIdx.x;
  int g0 = tid * 2, g1 = tid * 2 + 1;
  int v0 = (g0 < NB) ? btot[g0] : 0;
  int v1 = (g1 < NB) ? btot[g1] : 0;
  int tsum = v0 + v1;
  s[tid] = tsum;
  __syncthreads();
  for (int off = 1; off < 256; off <<= 1) {
    int t = (tid >= off) ? s[tid - off] : 0;
    __syncthreads();
    s[tid] += t;
    __syncthreads();
  }
  int run = s[tid] - tsum;
  if (g0 < NB) bbase[g0] = run;
  if (g1 < NB) bbase[g1] = run + v0;
  if (tid == 0) bbase[NB] = N_EDGES;
}

__global__ __launch_bounds__(256) void csr_place(
    const int* __restrict__ src, const int* __restrict__ dst,
    const int* __restrict__ counts, const int* __restrict__ bbase,
    unsigned* __restrict__ staged) {
  __shared__ int cur[NB];
  int w = blockIdx.x, tid = threadIdx.x;
  for (int i = tid; i < NB; i += 256) cur[i] = bbase[i] + counts[i * NWG + w];
  __syncthreads();
  const int4* d4 = (const int4*)(dst + w * CHUNK);
  const int4* s4 = (const int4*)(src + w * CHUNK);
  for (int i = tid; i < CHUNK / 4; i += 256) {
    int4 d = d4[i];
    int4 sv = s4[i];
    int p0 = atomicAdd(&cur[d.x >> BSHIFT], 1);
    staged[p0] = ((unsigned)sv.x << 8) | (unsigned)(d.x & (BNODES - 1));
    int p1 = atomicAdd(&cur[d.y >> BSHIFT], 1);
    staged[p1] = ((unsigned)sv.y << 8) | (unsigned)(d.y & (BNODES - 1));
    int p2 = atomicAdd(&cur[d.z >> BSHIFT], 1);
    staged[p2] = ((unsigned)sv.z << 8) | (unsigned)(d.z & (BNODES - 1));
    int p3 = atomicAdd(&cur[d.w >> BSHIFT], 1);
    staged[p3] = ((unsigned)sv.w << 8) | (unsigned)(d.w & (BNODES - 1));
  }
}

__global__ __launch_bounds__(256) void csr_fill(
    const unsigned* __restrict__ staged, const int* __restrict__ bbase,
    int* __restrict__ row_ptr, int* __restrict__ sorted_src) {
  __shared__ int s_cnt[BNODES];
  __shared__ int s_scan[BNODES];
  int b = blockIdx.x, tid = threadIdx.x;
  int n0 = b << BSHIFT;
  int beg = bbase[b], end = bbase[b + 1];
  s_cnt[tid] = 0;
  __syncthreads();
  for (int i = beg + tid; i < end; i += 256)
    atomicAdd(&s_cnt[staged[i] & (BNODES - 1)], 1);
  __syncthreads();
  int v = s_cnt[tid];
  s_scan[tid] = v;
  __syncthreads();
  for (int off = 1; off < BNODES; off <<= 1) {
    int t = (tid >= off) ? s_scan[tid - off] : 0;
    __syncthreads();
    s_scan[tid] += t;
    __syncthreads();
  }
  int excl = s_scan[tid] - v;
  int node = n0 + tid;
  if (node < N_NODES) row_ptr[node] = beg + excl;
  if (b == 0 && tid == 0) row_ptr[N_NODES] = N_EDGES;
  s_cnt[tid] = excl;
  __syncthreads();
  for (int i = beg + tid; i < end; i += 256) {
    unsigned p = staged[i];
    int r = atomicAdd(&s_cnt[p & (BNODES - 1)], 1);
    sorted_src[beg + r] = (int)(p >> 8);
  }
}

// ---------------------------------------------------------------------------
// Layer 1 (R16): fp8 L2-resident xq gather; 16 groups of 4 lanes x uint2,
// 2-deep; f16-packed shuffle tree; root f16; MFMA epilogue. Emits h1h (f16)
// and the SPLIT fp8 tables h1q_lo / h1q_hi (3.2 MB each, L2-fit).
// ---------------------------------------------------------------------------
#define F1 72   // feat stride (u16): 144B rows, 16B-aligned
__global__ __launch_bounds__(256) void layer1_fused(
    const u16* __restrict__ xh, const u8* __restrict__ xq,
    const int* __restrict__ row_ptr, const int* __restrict__ sorted_src,
    const u16* __restrict__ w_lf, const float* __restrict__ b_l,
    const u16* __restrict__ w_rf, u16* __restrict__ h1h,
    u8* __restrict__ h1q_lo, u8* __restrict__ h1q_hi) {
  __shared__ __align__(16) u16 s_feat[16 * F1];

  int tid = threadIdx.x;
  int w = tid >> 6, lane = tid & 63;
  int q = lane & 3, g = lane >> 2;  // 16 groups of 4; lane owns ch 8q..8q+7

  for (int m = 0; m < 4; ++m) {
    int nl = 4 * w + m;
    int node = blockIdx.x * 16 + nl;
    int rs = row_ptr[node];
    int deg = row_ptr[node + 1] - rs;
    f32x2 A0{}, A1{}, A2{}, A3{};
    f32x2 B0{}, B1{}, B2{}, B3{};
    int kk = g;
    for (; kk + 16 < deg; kk += 32) {
      int s0 = sorted_src[rs + kk];
      int s1 = sorted_src[rs + kk + 16];
      uint2 u0 = *(const uint2*)&xq[s0 * IN_DIM + 8 * q];
      uint2 u1 = *(const uint2*)&xq[s1 * IN_DIM + 8 * q];
      A0 += __builtin_amdgcn_cvt_pk_f32_fp8(u0.x, false);
      A1 += __builtin_amdgcn_cvt_pk_f32_fp8(u0.x, true);
      A2 += __builtin_amdgcn_cvt_pk_f32_fp8(u0.y, false);
      A3 += __builtin_amdgcn_cvt_pk_f32_fp8(u0.y, true);
      B0 += __builtin_amdgcn_cvt_pk_f32_fp8(u1.x, false);
      B1 += __builtin_amdgcn_cvt_pk_f32_fp8(u1.x, true);
      B2 += __builtin_amdgcn_cvt_pk_f32_fp8(u1.y, false);
      B3 += __builtin_amdgcn_cvt_pk_f32_fp8(u1.y, true);
    }
    if (kk < deg) {
      int s0 = sorted_src[rs + kk];
      uint2 u0 = *(const uint2*)&xq[s0 * IN_DIM + 8 * q];
      A0 += __builtin_amdgcn_cvt_pk_f32_fp8(u0.x, false);
      A1 += __builtin_amdgcn_cvt_pk_f32_fp8(u0.x, true);
      A2 += __builtin_amdgcn_cvt_pk_f32_fp8(u0.y, false);
      A3 += __builtin_amdgcn_cvt_pk_f32_fp8(u0.y, true);
    }
    A0 += B0; A1 += B1; A2 += B2; A3 += B3;
    h2 p0 = as_h2(pack2_h(A0.x, A0.y));
    h2 p1 = as_h2(pack2_h(A1.x, A1.y));
    h2 p2 = as_h2(pack2_h(A2.x, A2.y));
    h2 p3 = as_h2(pack2_h(A3.x, A3.y));
#pragma unroll
    for (int off = 4; off < 64; off <<= 1) {
      p0 += shfl_xor_h2(p0, off);
      p1 += shfl_xor_h2(p1, off);
      p2 += shfl_xor_h2(p2, off);
      p3 += shfl_xor_h2(p3, off);
    }
    if (g == 0) {
      float rinv = 1.0f / fmaxf((float)deg, 1.0f);
      uint4 o;
      o.x = scale_h2(as_u(p0), rinv);
      o.y = scale_h2(as_u(p1), rinv);
      o.z = scale_h2(as_u(p2), rinv);
      o.w = scale_h2(as_u(p3), rinv);
      *(uint4*)&s_feat[nl * F1 + 8 * q] = o;
    }
  }
  // root x copy (f16, exact path)
  {
    int nm = lane >> 4, q2 = lane & 15;
    int nl = 4 * w + nm;
    int node = blockIdx.x * 16 + nl;
    unsigned ux = *(const unsigned*)&xh[node * IN_DIM + 2 * q2];
    *(unsigned*)&s_feat[nl * F1 + IN_DIM + 2 * q2] = ux;
  }
  __syncthreads();

  int q16 = lane & 15, g4 = lane >> 4;
  int j = 16 * w + q16;
  half8 b0f = *(const half8*)&w_lf[j * IN_DIM + 8 * g4];
  half8 b1f = *(const half8*)&w_rf[j * IN_DIM + 8 * g4];
  half8 a0f = *(const half8*)&s_feat[q16 * F1 + 8 * g4];
  half8 a1f = *(const half8*)&s_feat[q16 * F1 + 32 + 8 * g4];
  float4v acc = {};
  acc = __builtin_amdgcn_mfma_f32_16x16x32_f16(a0f, b0f, acc, 0, 0, 0);
  acc = __builtin_amdgcn_mfma_f32_16x16x32_f16(a1f, b1f, acc, 0, 0, 0);
  float bj = b_l[j];
#pragma unroll
  for (int reg = 0; reg < 4; ++reg) {
    int nl = 4 * g4 + reg;
    float v = fmaxf(acc[reg] + bj, 0.0f);
    int node = blockIdx.x * 16 + nl;
    h1h[node * HID + j] = f2h(v);
    int enc = __builtin_amdgcn_cvt_pk_fp8_f32(v, v, 0, false);
    u8 e8 = (u8)(enc & 0xff);
    if (j < 32)
      h1q_lo[node * 32 + j] = e8;
    else
      h1q_hi[node * 32 + (j - 32)] = e8;
  }
}

// ---------------------------------------------------------------------------
// Layer 2 (R17): TWO phase-major gather passes over the split fp8 tables
// (each 3.2 MB -> per-XCD L2-resident, like layer1's xq). Per phase:
// 4 lanes/edge x uint2 (8 fp8 ch), 16 edge slots, 2-deep -> one serial
// round at deg~32, 8 f32x2 accumulators (no R15 VGPR blowup).
// Root f16; MFMA + classifier unchanged.
// ---------------------------------------------------------------------------
#define F2 136  // feat stride (u16): 272B rows, 16B-aligned
__global__ __launch_bounds__(256) void layer2_fused(
    const u16* __restrict__ h1h, const u8* __restrict__ h1q_lo,
    const u8* __restrict__ h1q_hi, const int* __restrict__ row_ptr,
    const int* __restrict__ sorted_src, const u16* __restrict__ w_lf,
    const float* __restrict__ b_l, const u16* __restrict__ w_rf,
    const float* __restrict__ wc, const float* __restrict__ bc,
    float* __restrict__ out) {
  __shared__ __align__(16) u16 s_feat[16 * F2];
  __shared__ float s_out[16];

  int tid = threadIdx.x;
  if (tid < 16) s_out[tid] = bc[0];

  int w = tid >> 6, lane = tid & 63;
  int q = lane & 3, g = lane >> 2;  // 16 edge slots of 4 lanes; 8 ch/lane

  for (int p = 0; p < 2; ++p) {
    const u8* tab = p ? h1q_hi : h1q_lo;
    for (int m = 0; m < 4; ++m) {
      int nl = 4 * w + m;
      int node = blockIdx.x * 16 + nl;
      int rs = row_ptr[node];
      int deg = row_ptr[node + 1] - rs;
      f32x2 A0{}, A1{}, A2{}, A3{};
      f32x2 B0{}, B1{}, B2{}, B3{};
      int kk = g;
      for (; kk + 16 < deg; kk += 32) {
        int s0 = sorted_src[rs + kk];
        int s1 = sorted_src[rs + kk + 16];
        uint2 u0 = *(const uint2*)&tab[s0 * 32 + 8 * q];
        uint2 u1 = *(const uint2*)&tab[s1 * 32 + 8 * q];
        A0 += __builtin_amdgcn_cvt_pk_f32_fp8(u0.x, false);
        A1 += __builtin_amdgcn_cvt_pk_f32_fp8(u0.x, true);
        A2 += __builtin_amdgcn_cvt_pk_f32_fp8(u0.y, false);
        A3 += __builtin_amdgcn_cvt_pk_f32_fp8(u0.y, true);
        B0 += __builtin_amdgcn_cvt_pk_f32_fp8(u1.x, false);
        B1 += __builtin_amdgcn_cvt_pk_f32_fp8(u1.x, true);
        B2 += __builtin_amdgcn_cvt_pk_f32_fp8(u1.y, false);
        B3 += __builtin_amdgcn_cvt_pk_f32_fp8(u1.y, true);
      }
      if (kk < deg) {
        int s0 = sorted_src[rs + kk];
        uint2 u0 = *(const uint2*)&tab[s0 * 32 + 8 * q];
        A0 += __builtin_amdgcn_cvt_pk_f32_fp8(u0.x, false);
        A1 += __builtin_amdgcn_cvt_pk_f32_fp8(u0.x, true);
        A2 += __builtin_amdgcn_cvt_pk_f32_fp8(u0.y, false);
        A3 += __builtin_amdgcn_cvt_pk_f32_fp8(u0.y, true);
      }
      A0 += B0; A1 += B1; A2 += B2; A3 += B3;
      h2 p0 = as_h2(pack2_h(A0.x, A0.y));
      h2 p1 = as_h2(pack2_h(A1.x, A1.y));
      h2 p2 = as_h2(pack2_h(A2.x, A2.y));
      h2 p3 = as_h2(pack2_h(A3.x, A3.y));
#pragma unroll
      for (int off = 4; off < 64; off <<= 1) {
        p0 += shfl_xor_h2(p0, off);
        p1 += shfl_xor_h2(p1, off);
        p2 += shfl_xor_h2(p2, off);
        p3 += shfl_xor_h2(p3, off);
      }
      if (g == 0) {
        float rinv = 1.0f / fmaxf((float)deg, 1.0f);
        uint4 o;
        o.x = scale_h2(as_u(p0), rinv);
        o.y = scale_h2(as_u(p1), rinv);
        o.z = scale_h2(as_u(p2), rinv);
        o.w = scale_h2(as_u(p3), rinv);
        *(uint4*)&s_feat[nl * F2 + 32 * p + 8 * q] = o;
      }
    }
  }
  // root h1 copy (f16, exact path): 16 lanes x 4ch each
  {
    int nm = lane >> 4, q2 = lane & 15;
    int nl = 4 * w + nm;
    int node = blockIdx.x * 16 + nl;
    uint2 uh = *(const uint2*)&h1h[node * HID + 4 * q2];
    *(uint2*)&s_feat[nl * F2 + HID + 4 * q2] = uh;
  }
  __syncthreads();

  int q16 = lane & 15, g4 = lane >> 4;
  int j = 16 * w + q16;
  half8 bf0 = *(const half8*)&w_lf[j * HID + 8 * g4];
  half8 bf1 = *(const half8*)&w_lf[j * HID + 32 + 8 * g4];
  half8 bf2 = *(const half8*)&w_rf[j * HID + 8 * g4];
  half8 bf3 = *(const half8*)&w_rf[j * HID + 32 + 8 * g4];
  float4v acc = {};
  acc = __builtin_amdgcn_mfma_f32_16x16x32_f16(
      *(const half8*)&s_feat[q16 * F2 + 8 * g4], bf0, acc, 0, 0, 0);
  acc = __builtin_amdgcn_mfma_f32_16x16x32_f16(
      *(const half8*)&s_feat[q16 * F2 + 32 + 8 * g4], bf1, acc, 0, 0, 0);
  acc = __builtin_amdgcn_mfma_f32_16x16x32_f16(
      *(const half8*)&s_feat[q16 * F2 + 64 + 8 * g4], bf2, acc, 0, 0, 0);
  acc = __builtin_amdgcn_mfma_f32_16x16x32_f16(
      *(const half8*)&s_feat[q16 * F2 + 96 + 8 * g4], bf3, acc, 0, 0, 0);
  float bj = b_l[j];
  float wcj = wc[j];
#pragma unroll
  for (int reg = 0; reg < 4; ++reg) {
    float v = fmaxf(acc[reg] + bj, 0.0f) * wcj;
    v += __shfl_xor(v, 1, 64);
    v += __shfl_xor(v, 2, 64);
    v += __shfl_xor(v, 4, 64);
    v += __shfl_xor(v, 8, 64);
    if (q16 == 0) atomicAdd(&s_out[4 * g4 + reg], v);
  }
  __syncthreads();
  if (tid < 16) out[blockIdx.x * 16 + tid] = s_out[tid];
}

// ---------------------------------------------------------------------------
extern "C" void kernel_launch(void* const* d_in, const int* in_sizes, int n_in,
                              void* d_out, int out_size, void* d_ws, size_t ws_size,
                              hipStream_t stream) {
  const float* x   = (const float*)d_in[0];
  const int*   ei  = (const int*)d_in[1];
  const float* w1l = (const float*)d_in[2];
  const float* b1l = (const float*)d_in[3];
  const float* w1r = (const float*)d_in[4];
  const float* w2l = (const float*)d_in[5];
  const float* b2l = (const float*)d_in[6];
  const float* w2r = (const float*)d_in[7];
  const float* wc  = (const float*)d_in[8];
  const float* bc  = (const float*)d_in[9];
  float* out = (float*)d_out;

  const int* src = ei;             // edge_index[0]
  const int* dst = ei + N_EDGES;   // edge_index[1]

  // workspace layout
  char* ws = (char*)d_ws;
  int*      row_ptr    = (int*)(ws + 0);          // 400,004 B
  int*      counts     = (int*)(ws + 400128);     // NB*NWG*4 = 400,384 B
  int*      btot       = (int*)(ws + 800768);     // 1,564 B
  int*      bbase      = (int*)(ws + 802560);     // 1,568 B
  unsigned* staged     = (unsigned*)(ws + 804352);// E*4 = 12.8 MB
  int*      sorted_src = (int*)(ws + 13604352);   // E*4 = 12.8 MB
  u16*      xh         = (u16*)(ws + 26404352);   // 6.4 MB
  u16*      h1h        = (u16*)(ws + 32804352);   // 12.8 MB
  u8*       h1q_lo     = (u8*)(ws + 45604352);    // 3.2 MB (fp8, L2-fit)
  u8*       h1q_hi     = (u8*)(ws + 48804352);    // 3.2 MB (fp8, L2-fit)
  u8*       xq         = (u8*)(ws + 52004352);    // 3.2 MB (fp8, L2-fit)
  u16*      w1lf       = (u16*)(ws + 55204352);   // 4 KB
  u16*      w1rf       = (u16*)(ws + 55208448);   // 4 KB
  u16*      w2lf       = (u16*)(ws + 55212544);   // 8 KB
  u16*      w2rf       = (u16*)(ws + 55220736);   // 8 KB
  // total 55,228,928 B

  csr_count<<<NWG + XBLOCKS + 1, 256, 0, stream>>>(
      dst, counts, x, xh, xq, w1l, w1r, w2l, w2r, w1lf, w1rf, w2lf, w2rf);
  csr_scan_w<<<NB, 256, 0, stream>>>(counts, btot);
  csr_scan_b<<<1, 256, 0, stream>>>(btot, bbase);
  csr_place<<<NWG, 256, 0, stream>>>(src, dst, counts, bbase, staged);
  csr_fill<<<NB, 256, 0, stream>>>(staged, bbase, row_ptr, sorted_src);
  layer1_fused<<<N_NODES / 16, 256, 0, stream>>>(xh, xq, row_ptr, sorted_src,
                                                 w1lf, b1l, w1rf, h1h,
                                                 h1q_lo, h1q_hi);
  layer2_fused<<<N_NODES / 16, 256, 0, stream>>>(h1h, h1q_lo, h1q_hi,
                                                 row_ptr, sorted_src,
                                                 w2lf, b2l, w2rf, wc, bc, out);
}

// Round 18
// 160.428 us; speedup vs baseline: 1.1639x; 1.1639x over previous
//
#include <hip/hip_runtime.h>

#define N_NODES 100000
#define N_EDGES 3200000
#define IN_DIM 32
#define HID 64
#define BSHIFT 8
#define BNODES 256                              // nodes per bucket
#define NB ((N_NODES + BNODES - 1) / BNODES)    // 391 buckets
#define NWG 256                                 // WGs for count/place
#define CHUNK (N_EDGES / NWG)                   // 12500 edges per WG (exact)
// segment bytes per (WG,bucket) = 4*CHUNK/NB ~= 128B >= 64B line (KEY!)
#define XBLOCKS ((N_NODES * IN_DIM + 255) / 256)  // 12500

typedef unsigned short u16;
typedef unsigned char u8;
typedef _Float16 h2 __attribute__((ext_vector_type(2)));
typedef _Float16 half8 __attribute__((ext_vector_type(8)));
typedef float float4v __attribute__((ext_vector_type(4)));
typedef float f32x2 __attribute__((ext_vector_type(2)));

__device__ __forceinline__ h2 as_h2(unsigned u) {
  return __builtin_bit_cast(h2, u);
}
__device__ __forceinline__ unsigned as_u(h2 v) {
  return __builtin_bit_cast(unsigned, v);
}
__device__ __forceinline__ h2 shfl_xor_h2(h2 v, int m) {
  int i = __builtin_bit_cast(int, v);
  i = __shfl_xor(i, m, 64);
  return __builtin_bit_cast(h2, i);
}
__device__ __forceinline__ f32x2 shfl_xor_f2(f32x2 v, int m) {
  f32x2 r;
  r.x = __shfl_xor(v.x, m, 64);
  r.y = __shfl_xor(v.y, m, 64);
  return r;
}
__device__ __forceinline__ u16 f2h(float f) {
  _Float16 h = (_Float16)f;
  return __builtin_bit_cast(u16, h);
}
__device__ __forceinline__ unsigned scale_h2(unsigned u, float rinv) {
  h2 v = as_h2(u);
  h2 o;
  o.x = (_Float16)((float)v.x * rinv);
  o.y = (_Float16)((float)v.y * rinv);
  return as_u(o);
}
__device__ __forceinline__ unsigned pack2_h(float a, float b) {
  h2 o;
  o.x = (_Float16)a;
  o.y = (_Float16)b;
  return as_u(o);
}

// ---------------------------------------------------------------------------
// csr_count (512 threads: 8 waves/CU for streaming) with FUSED prep:
// blocks [0,NWG) histogram; [NWG, NWG+XBLOCKS/2) convert x (512 elems each);
// last block converts weights.
// ---------------------------------------------------------------------------
__global__ __launch_bounds__(512) void csr_count(
    const int* __restrict__ dst, int* __restrict__ counts,
    const float* __restrict__ x, u16* __restrict__ xh, u8* __restrict__ xq,
    const float* __restrict__ w1l, const float* __restrict__ w1r,
    const float* __restrict__ w2l, const float* __restrict__ w2r,
    u16* __restrict__ w1lf, u16* __restrict__ w1rf,
    u16* __restrict__ w2lf, u16* __restrict__ w2rf) {
  int b = blockIdx.x, tid = threadIdx.x;
  if (b < NWG) {
    __shared__ int h[NB];
    for (int i = tid; i < NB; i += 512) h[i] = 0;
    __syncthreads();
    const int4* d4 = (const int4*)(dst + b * CHUNK);
    for (int i = tid; i < CHUNK / 4; i += 512) {
      int4 v = d4[i];
      atomicAdd(&h[v.x >> BSHIFT], 1);
      atomicAdd(&h[v.y >> BSHIFT], 1);
      atomicAdd(&h[v.z >> BSHIFT], 1);
      atomicAdd(&h[v.w >> BSHIFT], 1);
    }
    __syncthreads();
    for (int i = tid; i < NB; i += 512) counts[i * NWG + b] = h[i];
  } else if (b < NWG + (XBLOCKS + 1) / 2) {
    int i = (b - NWG) * 512 + tid;
    if (i < N_NODES * IN_DIM) {
      float v = x[i];
      xh[i] = f2h(v);
      int enc = __builtin_amdgcn_cvt_pk_fp8_f32(v, v, 0, false);
      xq[i] = (u8)(enc & 0xff);
    }
  } else {
    for (int i = tid; i < HID * IN_DIM; i += 512) {
      w1lf[i] = f2h(w1l[i]);
      w1rf[i] = f2h(w1r[i]);
    }
    for (int i = tid; i < HID * HID; i += 512) {
      w2lf[i] = f2h(w2l[i]);
      w2rf[i] = f2h(w2r[i]);
    }
  }
}

__global__ __launch_bounds__(256) void csr_scan_w(
    int* __restrict__ counts, int* __restrict__ btot) {
  __shared__ int s[256];
  int b = blockIdx.x, tid = threadIdx.x;
  int v = counts[b * NWG + tid];
  s[tid] = v;
  __syncthreads();
  for (int off = 1; off < 256; off <<= 1) {
    int t = (tid >= off) ? s[tid - off] : 0;
    __syncthreads();
    s[tid] += t;
    __syncthreads();
  }
  counts[b * NWG + tid] = s[tid] - v;
  if (tid == 255) btot[b] = s[255];
}

__global__ __launch_bounds__(256) void csr_scan_b(
    const int* __restrict__ btot, int* __restrict__ bbase) {
  __shared__ int s[256];
  int tid = threadIdx.x;
  int g0 = tid * 2, g1 = tid * 2 + 1;
  int v0 = (g0 < NB) ? btot[g0] : 0;
  int v1 = (g1 < NB) ? btot[g1] : 0;
  int tsum = v0 + v1;
  s[tid] = tsum;
  __syncthreads();
  for (int off = 1; off < 256; off <<= 1) {
    int t = (tid >= off) ? s[tid - off] : 0;
    __syncthreads();
    s[tid] += t;
    __syncthreads();
  }
  int run = s[tid] - tsum;
  if (g0 < NB) bbase[g0] = run;
  if (g1 < NB) bbase[g1] = run + v0;
  if (tid == 0) bbase[NB] = N_EDGES;
}

// 512 threads: 8 waves/CU.
__global__ __launch_bounds__(512) void csr_place(
    const int* __restrict__ src, const int* __restrict__ dst,
    const int* __restrict__ counts, const int* __restrict__ bbase,
    unsigned* __restrict__ staged) {
  __shared__ int cur[NB];
  int w = blockIdx.x, tid = threadIdx.x;
  for (int i = tid; i < NB; i += 512) cur[i] = bbase[i] + counts[i * NWG + w];
  __syncthreads();
  const int4* d4 = (const int4*)(dst + w * CHUNK);
  const int4* s4 = (const int4*)(src + w * CHUNK);
  for (int i = tid; i < CHUNK / 4; i += 512) {
    int4 d = d4[i];
    int4 sv = s4[i];
    int p0 = atomicAdd(&cur[d.x >> BSHIFT], 1);
    staged[p0] = ((unsigned)sv.x << 8) | (unsigned)(d.x & (BNODES - 1));
    int p1 = atomicAdd(&cur[d.y >> BSHIFT], 1);
    staged[p1] = ((unsigned)sv.y << 8) | (unsigned)(d.y & (BNODES - 1));
    int p2 = atomicAdd(&cur[d.z >> BSHIFT], 1);
    staged[p2] = ((unsigned)sv.z << 8) | (unsigned)(d.z & (BNODES - 1));
    int p3 = atomicAdd(&cur[d.w >> BSHIFT], 1);
    staged[p3] = ((unsigned)sv.w << 8) | (unsigned)(d.w & (BNODES - 1));
  }
}

// 512 threads; scan phase uses first 256.
__global__ __launch_bounds__(512) void csr_fill(
    const unsigned* __restrict__ staged, const int* __restrict__ bbase,
    int* __restrict__ row_ptr, int* __restrict__ sorted_src) {
  __shared__ int s_cnt[BNODES];
  __shared__ int s_scan[BNODES];
  int b = blockIdx.x, tid = threadIdx.x;
  int n0 = b << BSHIFT;
  int beg = bbase[b], end = bbase[b + 1];
  if (tid < BNODES) s_cnt[tid] = 0;
  __syncthreads();
  for (int i = beg + tid; i < end; i += 512)
    atomicAdd(&s_cnt[staged[i] & (BNODES - 1)], 1);
  __syncthreads();
  if (tid < BNODES) s_scan[tid] = s_cnt[tid];
  __syncthreads();
  for (int off = 1; off < BNODES; off <<= 1) {
    int t = (tid < BNODES && tid >= off) ? s_scan[tid - off] : 0;
    __syncthreads();
    if (tid < BNODES) s_scan[tid] += t;
    __syncthreads();
  }
  if (tid < BNODES) {
    int node = n0 + tid;
    int excl = s_scan[tid] - s_cnt[tid];
    if (node < N_NODES) row_ptr[node] = beg + excl;
    s_cnt[tid] = excl;  // relative cursor
  }
  if (b == 0 && tid == 0) row_ptr[N_NODES] = N_EDGES;
  __syncthreads();
  for (int i = beg + tid; i < end; i += 512) {
    unsigned p = staged[i];
    int r = atomicAdd(&s_cnt[p & (BNODES - 1)], 1);
    sorted_src[beg + r] = (int)(p >> 8);
  }
}

// ---------------------------------------------------------------------------
// Layer 1 (R16 frozen): fp8 L2-resident xq gather; 16 groups of 4 lanes x
// uint2, 2-deep; f16-packed shuffle tree; root f16; MFMA epilogue.
// Emits h1h (f16) + h1q (fp8, single 6.4MB table).
// ---------------------------------------------------------------------------
#define F1 72   // feat stride (u16): 144B rows, 16B-aligned
__global__ __launch_bounds__(256) void layer1_fused(
    const u16* __restrict__ xh, const u8* __restrict__ xq,
    const int* __restrict__ row_ptr, const int* __restrict__ sorted_src,
    const u16* __restrict__ w_lf, const float* __restrict__ b_l,
    const u16* __restrict__ w_rf, u16* __restrict__ h1h,
    u8* __restrict__ h1q) {
  __shared__ __align__(16) u16 s_feat[16 * F1];

  int tid = threadIdx.x;
  int w = tid >> 6, lane = tid & 63;
  int q = lane & 3, g = lane >> 2;  // 16 groups of 4; lane owns ch 8q..8q+7

  for (int m = 0; m < 4; ++m) {
    int nl = 4 * w + m;
    int node = blockIdx.x * 16 + nl;
    int rs = row_ptr[node];
    int deg = row_ptr[node + 1] - rs;
    f32x2 A0{}, A1{}, A2{}, A3{};
    f32x2 B0{}, B1{}, B2{}, B3{};
    int kk = g;
    for (; kk + 16 < deg; kk += 32) {
      int s0 = sorted_src[rs + kk];
      int s1 = sorted_src[rs + kk + 16];
      uint2 u0 = *(const uint2*)&xq[s0 * IN_DIM + 8 * q];
      uint2 u1 = *(const uint2*)&xq[s1 * IN_DIM + 8 * q];
      A0 += __builtin_amdgcn_cvt_pk_f32_fp8(u0.x, false);
      A1 += __builtin_amdgcn_cvt_pk_f32_fp8(u0.x, true);
      A2 += __builtin_amdgcn_cvt_pk_f32_fp8(u0.y, false);
      A3 += __builtin_amdgcn_cvt_pk_f32_fp8(u0.y, true);
      B0 += __builtin_amdgcn_cvt_pk_f32_fp8(u1.x, false);
      B1 += __builtin_amdgcn_cvt_pk_f32_fp8(u1.x, true);
      B2 += __builtin_amdgcn_cvt_pk_f32_fp8(u1.y, false);
      B3 += __builtin_amdgcn_cvt_pk_f32_fp8(u1.y, true);
    }
    if (kk < deg) {
      int s0 = sorted_src[rs + kk];
      uint2 u0 = *(const uint2*)&xq[s0 * IN_DIM + 8 * q];
      A0 += __builtin_amdgcn_cvt_pk_f32_fp8(u0.x, false);
      A1 += __builtin_amdgcn_cvt_pk_f32_fp8(u0.x, true);
      A2 += __builtin_amdgcn_cvt_pk_f32_fp8(u0.y, false);
      A3 += __builtin_amdgcn_cvt_pk_f32_fp8(u0.y, true);
    }
    A0 += B0; A1 += B1; A2 += B2; A3 += B3;
    h2 p0 = as_h2(pack2_h(A0.x, A0.y));
    h2 p1 = as_h2(pack2_h(A1.x, A1.y));
    h2 p2 = as_h2(pack2_h(A2.x, A2.y));
    h2 p3 = as_h2(pack2_h(A3.x, A3.y));
#pragma unroll
    for (int off = 4; off < 64; off <<= 1) {
      p0 += shfl_xor_h2(p0, off);
      p1 += shfl_xor_h2(p1, off);
      p2 += shfl_xor_h2(p2, off);
      p3 += shfl_xor_h2(p3, off);
    }
    if (g == 0) {
      float rinv = 1.0f / fmaxf((float)deg, 1.0f);
      uint4 o;
      o.x = scale_h2(as_u(p0), rinv);
      o.y = scale_h2(as_u(p1), rinv);
      o.z = scale_h2(as_u(p2), rinv);
      o.w = scale_h2(as_u(p3), rinv);
      *(uint4*)&s_feat[nl * F1 + 8 * q] = o;
    }
  }
  // root x copy (f16, exact path)
  {
    int nm = lane >> 4, q2 = lane & 15;
    int nl = 4 * w + nm;
    int node = blockIdx.x * 16 + nl;
    unsigned ux = *(const unsigned*)&xh[node * IN_DIM + 2 * q2];
    *(unsigned*)&s_feat[nl * F1 + IN_DIM + 2 * q2] = ux;
  }
  __syncthreads();

  int q16 = lane & 15, g4 = lane >> 4;
  int j = 16 * w + q16;
  half8 b0f = *(const half8*)&w_lf[j * IN_DIM + 8 * g4];
  half8 b1f = *(const half8*)&w_rf[j * IN_DIM + 8 * g4];
  half8 a0f = *(const half8*)&s_feat[q16 * F1 + 8 * g4];
  half8 a1f = *(const half8*)&s_feat[q16 * F1 + 32 + 8 * g4];
  float4v acc = {};
  acc = __builtin_amdgcn_mfma_f32_16x16x32_f16(a0f, b0f, acc, 0, 0, 0);
  acc = __builtin_amdgcn_mfma_f32_16x16x32_f16(a1f, b1f, acc, 0, 0, 0);
  float bj = b_l[j];
#pragma unroll
  for (int reg = 0; reg < 4; ++reg) {
    int nl = 4 * g4 + reg;
    float v = fmaxf(acc[reg] + bj, 0.0f);
    int node = blockIdx.x * 16 + nl;
    h1h[node * HID + j] = f2h(v);
    int enc = __builtin_amdgcn_cvt_pk_fp8_f32(v, v, 0, false);
    h1q[node * HID + j] = (u8)(enc & 0xff);
  }
}

// ---------------------------------------------------------------------------
// Layer 2 (R14 VERBATIM — measured floor 63.4us): fp8 h1q gather, 8 groups
// of 8 lanes x uint2, 2-deep; f32x2 accumulate; root f16; MFMA + classifier.
// ---------------------------------------------------------------------------
#define F2 136  // feat stride (u16): 272B rows, 16B-aligned
__global__ __launch_bounds__(256) void layer2_fused(
    const u16* __restrict__ h1h, const u8* __restrict__ h1q,
    const int* __restrict__ row_ptr, const int* __restrict__ sorted_src,
    const u16* __restrict__ w_lf, const float* __restrict__ b_l,
    const u16* __restrict__ w_rf, const float* __restrict__ wc,
    const float* __restrict__ bc, float* __restrict__ out) {
  __shared__ __align__(16) u16 s_feat[16 * F2];
  __shared__ float s_out[16];

  int tid = threadIdx.x;
  if (tid < 16) s_out[tid] = bc[0];

  int w = tid >> 6, lane = tid & 63;
  int q = lane & 7, g = lane >> 3;  // 8 groups of 8; lane owns ch 8q..8q+7

  for (int m = 0; m < 4; ++m) {
    int nl = 4 * w + m;
    int node = blockIdx.x * 16 + nl;
    int rs = row_ptr[node];
    int deg = row_ptr[node + 1] - rs;
    f32x2 a0{}, a1{}, a2{}, a3{};
    f32x2 b0{}, b1{}, b2{}, b3{};
    int kk = g;
    for (; kk + 8 < deg; kk += 16) {
      int s0 = sorted_src[rs + kk];
      int s1 = sorted_src[rs + kk + 8];
      uint2 u0 = *(const uint2*)&h1q[s0 * HID + 8 * q];
      uint2 u1 = *(const uint2*)&h1q[s1 * HID + 8 * q];
      a0 += __builtin_amdgcn_cvt_pk_f32_fp8(u0.x, false);
      a1 += __builtin_amdgcn_cvt_pk_f32_fp8(u0.x, true);
      a2 += __builtin_amdgcn_cvt_pk_f32_fp8(u0.y, false);
      a3 += __builtin_amdgcn_cvt_pk_f32_fp8(u0.y, true);
      b0 += __builtin_amdgcn_cvt_pk_f32_fp8(u1.x, false);
      b1 += __builtin_amdgcn_cvt_pk_f32_fp8(u1.x, true);
      b2 += __builtin_amdgcn_cvt_pk_f32_fp8(u1.y, false);
      b3 += __builtin_amdgcn_cvt_pk_f32_fp8(u1.y, true);
    }
    if (kk < deg) {
      int s0 = sorted_src[rs + kk];
      uint2 u0 = *(const uint2*)&h1q[s0 * HID + 8 * q];
      a0 += __builtin_amdgcn_cvt_pk_f32_fp8(u0.x, false);
      a1 += __builtin_amdgcn_cvt_pk_f32_fp8(u0.x, true);
      a2 += __builtin_amdgcn_cvt_pk_f32_fp8(u0.y, false);
      a3 += __builtin_amdgcn_cvt_pk_f32_fp8(u0.y, true);
    }
    a0 += b0; a1 += b1; a2 += b2; a3 += b3;
#pragma unroll
    for (int off = 8; off < 64; off <<= 1) {
      a0 += shfl_xor_f2(a0, off);
      a1 += shfl_xor_f2(a1, off);
      a2 += shfl_xor_f2(a2, off);
      a3 += shfl_xor_f2(a3, off);
    }
    if (g == 0) {   // lanes 0-7 hold the full 64-ch row (8 ch each)
      float rinv = 1.0f / fmaxf((float)deg, 1.0f);
      uint4 o;
      o.x = pack2_h(a0.x * rinv, a0.y * rinv);
      o.y = pack2_h(a1.x * rinv, a1.y * rinv);
      o.z = pack2_h(a2.x * rinv, a2.y * rinv);
      o.w = pack2_h(a3.x * rinv, a3.y * rinv);
      *(uint4*)&s_feat[nl * F2 + 8 * q] = o;
    }
  }
  // root h1 copy (f16, exact path): 16 lanes x 4ch each
  {
    int nm = lane >> 4, q2 = lane & 15;
    int nl = 4 * w + nm;
    int node = blockIdx.x * 16 + nl;
    uint2 uh = *(const uint2*)&h1h[node * HID + 4 * q2];
    *(uint2*)&s_feat[nl * F2 + HID + 4 * q2] = uh;
  }
  __syncthreads();

  int q16 = lane & 15, g4 = lane >> 4;
  int j = 16 * w + q16;
  half8 bf0 = *(const half8*)&w_lf[j * HID + 8 * g4];
  half8 bf1 = *(const half8*)&w_lf[j * HID + 32 + 8 * g4];
  half8 bf2 = *(const half8*)&w_rf[j * HID + 8 * g4];
  half8 bf3 = *(const half8*)&w_rf[j * HID + 32 + 8 * g4];
  float4v acc = {};
  acc = __builtin_amdgcn_mfma_f32_16x16x32_f16(
      *(const half8*)&s_feat[q16 * F2 + 8 * g4], bf0, acc, 0, 0, 0);
  acc = __builtin_amdgcn_mfma_f32_16x16x32_f16(
      *(const half8*)&s_feat[q16 * F2 + 32 + 8 * g4], bf1, acc, 0, 0, 0);
  acc = __builtin_amdgcn_mfma_f32_16x16x32_f16(
      *(const half8*)&s_feat[q16 * F2 + 64 + 8 * g4], bf2, acc, 0, 0, 0);
  acc = __builtin_amdgcn_mfma_f32_16x16x32_f16(
      *(const half8*)&s_feat[q16 * F2 + 96 + 8 * g4], bf3, acc, 0, 0, 0);
  float bj = b_l[j];
  float wcj = wc[j];
#pragma unroll
  for (int reg = 0; reg < 4; ++reg) {
    float v = fmaxf(acc[reg] + bj, 0.0f) * wcj;
    v += __shfl_xor(v, 1, 64);
    v += __shfl_xor(v, 2, 64);
    v += __shfl_xor(v, 4, 64);
    v += __shfl_xor(v, 8, 64);
    if (q16 == 0) atomicAdd(&s_out[4 * g4 + reg], v);
  }
  __syncthreads();
  if (tid < 16) out[blockIdx.x * 16 + tid] = s_out[tid];
}

// ---------------------------------------------------------------------------
extern "C" void kernel_launch(void* const* d_in, const int* in_sizes, int n_in,
                              void* d_out, int out_size, void* d_ws, size_t ws_size,
                              hipStream_t stream) {
  const float* x   = (const float*)d_in[0];
  const int*   ei  = (const int*)d_in[1];
  const float* w1l = (const float*)d_in[2];
  const float* b1l = (const float*)d_in[3];
  const float* w1r = (const float*)d_in[4];
  const float* w2l = (const float*)d_in[5];
  const float* b2l = (const float*)d_in[6];
  const float* w2r = (const float*)d_in[7];
  const float* wc  = (const float*)d_in[8];
  const float* bc  = (const float*)d_in[9];
  float* out = (float*)d_out;

  const int* src = ei;             // edge_index[0]
  const int* dst = ei + N_EDGES;   // edge_index[1]

  // workspace layout
  char* ws = (char*)d_ws;
  int*      row_ptr    = (int*)(ws + 0);          // 400,004 B
  int*      counts     = (int*)(ws + 400128);     // NB*NWG*4 = 400,384 B
  int*      btot       = (int*)(ws + 800768);     // 1,564 B
  int*      bbase      = (int*)(ws + 802560);     // 1,568 B
  unsigned* staged     = (unsigned*)(ws + 804352);// E*4 = 12.8 MB
  int*      sorted_src = (int*)(ws + 13604352);   // E*4 = 12.8 MB
  u16*      xh         = (u16*)(ws + 26404352);   // 6.4 MB
  u16*      h1h        = (u16*)(ws + 32804352);   // 12.8 MB
  u8*       h1q        = (u8*)(ws + 45604352);    // 6.4 MB (fp8 h1 table)
  u8*       xq         = (u8*)(ws + 52004352);    // 3.2 MB (fp8 x, L2-fit)
  u16*      w1lf       = (u16*)(ws + 55204352);   // 4 KB
  u16*      w1rf       = (u16*)(ws + 55208448);   // 4 KB
  u16*      w2lf       = (u16*)(ws + 55212544);   // 8 KB
  u16*      w2rf       = (u16*)(ws + 55220736);   // 8 KB
  // total 55,228,928 B

  csr_count<<<NWG + (XBLOCKS + 1) / 2 + 1, 512, 0, stream>>>(
      dst, counts, x, xh, xq, w1l, w1r, w2l, w2r, w1lf, w1rf, w2lf, w2rf);
  csr_scan_w<<<NB, 256, 0, stream>>>(counts, btot);
  csr_scan_b<<<1, 256, 0, stream>>>(btot, bbase);
  csr_place<<<NWG, 512, 0, stream>>>(src, dst, counts, bbase, staged);
  csr_fill<<<NB, 512, 0, stream>>>(staged, bbase, row_ptr, sorted_src);
  layer1_fused<<<N_NODES / 16, 256, 0, stream>>>(xh, xq, row_ptr, sorted_src,
                                                 w1lf, b1l, w1rf, h1h, h1q);
  layer2_fused<<<N_NODES / 16, 256, 0, stream>>>(h1h, h1q, row_ptr, sorted_src,
                                                 w2lf, b2l, w2rf, wc, bc, out);
}